// Round 1
// 281.182 us; speedup vs baseline: 1.2446x; 1.2446x over previous
//
#include <hip/hip_runtime.h>

#define Bdim 256
#define Tdim 512
#define Kdim 128
#define NT   512   // 4 threads per state

// One block per batch element, 512 threads (8 waves).
// Thread (j = tid>>2, g = tid&3) owns states-column j, i-range [g*32, g*32+32).
// E slice kept in 32 VGPRs per thread (no spill, unlike the 128-VGPR version).
// alpha in LINEAR space (A = exp(alpha - off)), renormalized by A[0] each step.
// Per step: 8 broadcast float4 LDS reads (bank-staggered by (u+g)&7), 32 FMAs,
// 2x shfl_xor cross-group reduce, one barrier.
__global__ __launch_bounds__(NT, 1) void crf_nll_kernel(
    const float* __restrict__ logits,   // B*T*K fp32
    const int*   __restrict__ labels,   // B*T   int32
    const int*   __restrict__ seq_lens, // B     int32
    const float* __restrict__ trans,    // K*K   fp32
    float* __restrict__ out)            // 1     fp32 (pre-zeroed)
{
    const int b   = blockIdx.x;
    const int tid = threadIdx.x;
    const int j   = tid >> 2;          // state 0..127
    const int g   = tid & 3;           // i-range group 0..3
    const int L   = seq_lens[b];       // 1..T (uniform per block)

    __shared__ float pbuf[2][Kdim];
    __shared__ float sred[NT / 64];
    __shared__ float ared[NT / 64];

    const int*   lab_b   = labels + (size_t)b * Tdim;
    const float* logit_b = logits + (size_t)b * Tdim * Kdim;

    // ---- E fragment in registers, rotated so LDS reads are bank-staggered:
    // e[u*4+c] = exp(trans[(g*32 + ((u+g)&7)*4 + c) * K + j])
    float e[32];
    #pragma unroll
    for (int u = 0; u < 8; ++u) {
        const int row0 = g * 32 + (((u + g) & 7) << 2);
        #pragma unroll
        for (int c = 0; c < 4; ++c)
            e[u * 4 + c] = __expf(trans[(row0 + c) * Kdim + j]);
    }

    // ---- gold-path score: thread t = tid handles one timestep ----
    float s = 0.f;
    {
        const int t = tid;
        if (t < L) {
            const int lb = lab_b[t];
            s = logit_b[(size_t)t * Kdim + lb];
            if (t >= 1) s += trans[lab_b[t - 1] * Kdim + lb];
        }
    }
    #pragma unroll
    for (int o = 32; o > 0; o >>= 1) s += __shfl_down(s, o, 64);
    if ((tid & 63) == 0) sred[tid >> 6] = s;

    // ---- init alpha (t = 0), linear space; only g==0 lanes own a state ----
    float a = 0.f, off = 0.f;
    if (g == 0) {
        a = __expf(logit_b[j]);
        pbuf[0][j] = a;
    }
    int cb = 0;
    __syncthreads();

    float score = 0.f;
    if (tid == 0) {
        #pragma unroll
        for (int w = 0; w < NT / 64; ++w) score += sred[w];
    }

    // ---- prefetch first logit chunk (t = 1..8) ----
    float curl[8], nxtl[8];
    #pragma unroll
    for (int u = 0; u < 8; ++u) {
        const int tt = 1 + u;
        curl[u] = (tt < Tdim) ? logit_b[(size_t)tt * Kdim + j] : 0.f;
    }

    // ---- forward recursion ----
    for (int tb = 1; tb < L; tb += 8) {
        #pragma unroll
        for (int u = 0; u < 8; ++u) {        // prefetch next chunk
            const int tt = tb + 8 + u;
            nxtl[u] = (tt < Tdim) ? logit_b[(size_t)tt * Kdim + j] : 0.f;
        }
        #pragma unroll
        for (int u = 0; u < 8; ++u) {
            const int t = tb + u;
            if (t < L) {                     // uniform per block
                const float4* p4 = (const float4*)pbuf[cb];
                float p0 = 1.f;
                float acc0 = 0.f, acc1 = 0.f, acc2 = 0.f, acc3 = 0.f;
                #pragma unroll
                for (int uu = 0; uu < 8; ++uu) {
                    const int idx = (g << 3) + ((uu + g) & 7);  // bank-staggered
                    const float4 p = p4[idx];
                    if (uu == 0) {           // g==0's uu=0 read is p4[0] -> A[0]
                        if (g == 0) p0 = p.x;
                    }
                    acc0 = fmaf(p.x, e[uu * 4 + 0], acc0);
                    acc1 = fmaf(p.y, e[uu * 4 + 1], acc1);
                    acc2 = fmaf(p.z, e[uu * 4 + 2], acc2);
                    acc3 = fmaf(p.w, e[uu * 4 + 3], acc3);
                }
                const float lp0 = __logf(p0);        // off-critical-path (g==0)
                float acc = (acc0 + acc1) + (acc2 + acc3);
                acc += __shfl_xor(acc, 1, 64);
                acc += __shfl_xor(acc, 2, 64);
                if (g == 0) {
                    a = acc * __expf(curl[u] - lp0);
                    off += lp0;
                    pbuf[cb ^ 1][j] = a;
                }
                cb ^= 1;
                __syncthreads();             // one barrier per step
            }
        }
        #pragma unroll
        for (int u = 0; u < 8; ++u) curl[u] = nxtl[u];
    }

    // ---- log_z = off + log(sum_j A[j]); nll = log_z - score ----
    float as = (g == 0) ? a : 0.f;
    #pragma unroll
    for (int o = 32; o > 0; o >>= 1) as += __shfl_down(as, o, 64);
    if ((tid & 63) == 0) ared[tid >> 6] = as;
    __syncthreads();
    if (tid == 0) {
        float tot = 0.f;
        #pragma unroll
        for (int w = 0; w < NT / 64; ++w) tot += ared[w];
        const float logz = off + __logf(tot);
        atomicAdd(out, logz - score);
    }
}

extern "C" void kernel_launch(void* const* d_in, const int* in_sizes, int n_in,
                              void* d_out, int out_size, void* d_ws, size_t ws_size,
                              hipStream_t stream) {
    const float* logits   = (const float*)d_in[0];
    const int*   labels   = (const int*)d_in[1];
    const int*   seq_lens = (const int*)d_in[2];
    const float* trans    = (const float*)d_in[3];
    float* out = (float*)d_out;

    hipMemsetAsync(out, 0, sizeof(float), stream);
    crf_nll_kernel<<<dim3(Bdim), dim3(NT), 0, stream>>>(
        logits, labels, seq_lens, trans, out);
}

// Round 3
// 268.836 us; speedup vs baseline: 1.3018x; 1.0459x over previous
//
#include <hip/hip_runtime.h>

#define Bdim 256
#define Tdim 512
#define Kdim 128
#define NT   512   // 4 threads per state

// Raw barrier: drain LDS ops only (NOT vmcnt) so global prefetches stay in
// flight across steps; then s_barrier. "memory" stops compiler reordering.
#define BAR() asm volatile("s_waitcnt lgkmcnt(0)\n\ts_barrier" ::: "memory")

// Quad-lane butterfly add via DPP (lanes 4j..4j+3 are one column group).
// CTRL 0xB1 = quad_perm [1,0,3,2] (xor 1); 0x4E = [2,3,0,1] (xor 2).
// DPP control must be an integer-constant expression -> template parameter.
template <int CTRL>
__device__ __forceinline__ float quad_add(float v) {
    int r = __builtin_amdgcn_update_dpp(0, __float_as_int(v), CTRL, 0xF, 0xF, true);
    return v + __int_as_float(r);
}

// One block per batch element, 512 threads (8 waves).
// Thread (j = tid>>2, g = tid&3) owns states-column j, i-range [g*32, g*32+32).
// E slice in 32 VGPRs. alpha in LINEAR space, renormalized by A[0] each step.
// Per step: 8 broadcast float4 LDS reads (bank-staggered), 32 FMAs,
// 2 DPP quad-adds, one lgkm-only barrier.
__global__ __launch_bounds__(NT, 1) void crf_nll_kernel(
    const float* __restrict__ logits,   // B*T*K fp32
    const int*   __restrict__ labels,   // B*T   int32
    const int*   __restrict__ seq_lens, // B     int32
    const float* __restrict__ trans,    // K*K   fp32
    float* __restrict__ out)            // 1     fp32 (pre-zeroed)
{
    const int b   = blockIdx.x;
    const int tid = threadIdx.x;
    const int j   = tid >> 2;          // state 0..127
    const int g   = tid & 3;           // i-range group 0..3
    const int L   = seq_lens[b];       // 1..T (uniform per block)

    __shared__ float pbuf[2][Kdim];
    __shared__ float sred[NT / 64];
    __shared__ float ared[NT / 64];

    const int*   lab_b   = labels + (size_t)b * Tdim;
    const float* logit_b = logits + (size_t)b * Tdim * Kdim;

    // ---- E fragment in registers, rotated so LDS reads are bank-staggered:
    // e[u*4+c] = exp(trans[(g*32 + ((u+g)&7)*4 + c) * K + j])
    float e[32];
    #pragma unroll
    for (int u = 0; u < 8; ++u) {
        const int row0 = g * 32 + (((u + g) & 7) << 2);
        #pragma unroll
        for (int c = 0; c < 4; ++c)
            e[u * 4 + c] = __expf(trans[(row0 + c) * Kdim + j]);
    }

    // ---- gold-path score: thread t = tid handles one timestep ----
    float s = 0.f;
    {
        const int t = tid;
        if (t < L) {
            const int lb = lab_b[t];
            s = logit_b[(size_t)t * Kdim + lb];
            if (t >= 1) s += trans[lab_b[t - 1] * Kdim + lb];
        }
    }
    #pragma unroll
    for (int o = 32; o > 0; o >>= 1) s += __shfl_down(s, o, 64);
    if ((tid & 63) == 0) sred[tid >> 6] = s;

    // ---- init alpha (t = 0), linear space; only g==0 lanes own a state ----
    float a = 0.f, off = 0.f;
    if (g == 0) {
        a = __expf(logit_b[j]);
        pbuf[0][j] = a;
    }
    int cb = 0;
    __syncthreads();

    float score = 0.f;
    if (tid == 0) {
        #pragma unroll
        for (int w = 0; w < NT / 64; ++w) score += sred[w];
    }

    // ---- prefetch first logit chunk (t = 1..8) ----
    float curl[8], nxtl[8];
    #pragma unroll
    for (int u = 0; u < 8; ++u) {
        const int tt = 1 + u;
        curl[u] = (tt < Tdim) ? logit_b[(size_t)tt * Kdim + j] : 0.f;
    }

    // ---- forward recursion ----
    for (int tb = 1; tb < L; tb += 8) {
        #pragma unroll
        for (int u = 0; u < 8; ++u) {        // prefetch next chunk
            const int tt = tb + 8 + u;
            nxtl[u] = (tt < Tdim) ? logit_b[(size_t)tt * Kdim + j] : 0.f;
        }
        #pragma unroll
        for (int u = 0; u < 8; ++u) {
            const int t = tb + u;
            if (t < L) {                     // uniform per block
                const float4* p4 = (const float4*)pbuf[cb];
                float p0 = 1.f;
                float acc0 = 0.f, acc1 = 0.f, acc2 = 0.f, acc3 = 0.f;
                #pragma unroll
                for (int uu = 0; uu < 8; ++uu) {
                    const int idx = (g << 3) + ((uu + g) & 7);  // bank-staggered
                    const float4 p = p4[idx];
                    if (uu == 0) {           // g==0's uu=0 read is p4[0] -> A[0]
                        if (g == 0) p0 = p.x;
                    }
                    acc0 = fmaf(p.x, e[uu * 4 + 0], acc0);
                    acc1 = fmaf(p.y, e[uu * 4 + 1], acc1);
                    acc2 = fmaf(p.z, e[uu * 4 + 2], acc2);
                    acc3 = fmaf(p.w, e[uu * 4 + 3], acc3);
                }
                const float lp0 = __logf(p0);        // off-critical-path (g==0)
                float acc = (acc0 + acc1) + (acc2 + acc3);
                acc = quad_add<0xB1>(acc);           // xor 1 within quad
                acc = quad_add<0x4E>(acc);           // xor 2 within quad
                if (g == 0) {
                    a = acc * __expf(curl[u] - lp0);
                    off += lp0;
                    pbuf[cb ^ 1][j] = a;
                }
                cb ^= 1;
                BAR();                       // lgkm-only barrier per step
            }
        }
        #pragma unroll
        for (int u = 0; u < 8; ++u) curl[u] = nxtl[u];
    }

    // ---- log_z = off + log(sum_j A[j]); nll = log_z - score ----
    float as = (g == 0) ? a : 0.f;
    #pragma unroll
    for (int o = 32; o > 0; o >>= 1) as += __shfl_down(as, o, 64);
    if ((tid & 63) == 0) ared[tid >> 6] = as;
    __syncthreads();
    if (tid == 0) {
        float tot = 0.f;
        #pragma unroll
        for (int w = 0; w < NT / 64; ++w) tot += ared[w];
        const float logz = off + __logf(tot);
        atomicAdd(out, logz - score);
    }
}

extern "C" void kernel_launch(void* const* d_in, const int* in_sizes, int n_in,
                              void* d_out, int out_size, void* d_ws, size_t ws_size,
                              hipStream_t stream) {
    const float* logits   = (const float*)d_in[0];
    const int*   labels   = (const int*)d_in[1];
    const int*   seq_lens = (const int*)d_in[2];
    const float* trans    = (const float*)d_in[3];
    float* out = (float*)d_out;

    (void)hipMemsetAsync(out, 0, sizeof(float), stream);
    crf_nll_kernel<<<dim3(Bdim), dim3(NT), 0, stream>>>(
        logits, labels, seq_lens, trans, out);
}